// Round 2
// baseline (463.139 us; speedup 1.0000x reference)
//
#include <hip/hip_runtime.h>
#include <math.h>

#define BB 16
#define AA 65536
#define GG 32

// workspace layout (bytes)
#define OFF_PACKED   0            // u64[BB*GG]                      4096
#define OFF_HIST     4096         // int[4][BB][256]                 65536
#define OFF_NUMPOS   69632        // int[BB]
#define OFF_LOCSUM   69696        // float[BB]
#define OFF_POSBCE   69760        // float[BB]
#define OFF_PREDCNT  69824        // int[BB]
#define OFF_NEGSUM   69888        // float[BB]
#define OFF_NGT      69952        // int[BB]
#define OFF_MIOU_S   70016        // float
#define OFF_MIOU_C   70020        // int
#define OFF_VK       70080        // float[BB]   (only read when k0>0, gated)
#define MEMSET_BYTES 71680        // zero [0, 70KiB)
#define OFF_BESTIOU  2097152      // float[BB*AA]                    4 MiB
#define OFF_BESTIDX  6291456      // u8[BB*AA]                       1 MiB
#define OFF_NEGBCE   7340032      // float[BB*AA]                    4 MiB

__device__ __forceinline__ float iou_exact(float ax, float ay, float az, float aw,
                                           float area_a,
                                           float gx, float gy, float gz, float gw,
                                           float area_g) {
    float lx = fmaxf(ax, gx), ly = fmaxf(ay, gy);
    float rx = fminf(az, gz), ry = fminf(aw, gw);
    float w = fmaxf(__fsub_rn(rx, lx), 0.0f);
    float h = fmaxf(__fsub_rn(ry, ly), 0.0f);
    float inter = __fmul_rn(w, h);
    float uni = __fsub_rn(__fadd_rn(area_a, area_g), inter);
    return __fdiv_rn(inter, __fadd_rn(uni, 1e-6f));
}

__device__ __forceinline__ float sl1(float x, float y) {
    float d = fabsf(__fsub_rn(x, y));
    return (d < 1.0f) ? __fmul_rn(__fmul_rn(0.5f, d), d) : __fsub_rn(d, 0.5f);
}

// ---------------- K1: IoU, per-anchor best, per-gt argmax via filtered LDS atomicMax ----------------
__global__ __launch_bounds__(256) void k_iou(const float4* __restrict__ anchors,
                                             const float4* __restrict__ gt,
                                             float* __restrict__ best_iou,
                                             unsigned char* __restrict__ best_idx,
                                             unsigned long long* __restrict__ packed) {
    const int b = blockIdx.y;
    const int t = threadIdx.x;
    __shared__ float4 gts[GG];
    __shared__ float areag[GG];
    __shared__ unsigned long long red[GG];
    __shared__ unsigned int red_hi[GG];
    if (t < GG) {
        float4 g4 = gt[b * GG + t];
        gts[t] = g4;
        areag[t] = __fmul_rn(__fsub_rn(g4.z, g4.x), __fsub_rn(g4.w, g4.y));
        red[t] = 0ull;
        red_hi[t] = 0u;
    }
    __syncthreads();
    const int base = blockIdx.x * 1024;
    float4 an[4]; float aa[4]; float bi[4]; int bix[4]; int aidx[4];
#pragma unroll
    for (int j = 0; j < 4; ++j) {
        aidx[j] = base + j * 256 + t;
        an[j] = anchors[aidx[j]];
        aa[j] = __fmul_rn(__fsub_rn(an[j].z, an[j].x), __fsub_rn(an[j].w, an[j].y));
        bi[j] = -1.0f; bix[j] = 0;
    }
    for (int g = 0; g < GG; ++g) {
        float4 gb = gts[g];
        float ag = areag[g];
        unsigned long long pk = 0ull;
#pragma unroll
        for (int j = 0; j < 4; ++j) {
            float iou = iou_exact(an[j].x, an[j].y, an[j].z, an[j].w, aa[j],
                                  gb.x, gb.y, gb.z, gb.w, ag);
            if (iou > bi[j]) { bi[j] = iou; bix[j] = g; }
            unsigned long long p = ((unsigned long long)__float_as_uint(iou) << 32)
                                 | (unsigned long long)(0xFFFFFFFFu - (unsigned)aidx[j]);
            if (p > pk) pk = p;
        }
        // racy-read filter (conservative: stale-low reads just cause an extra atomic)
        if ((unsigned int)(pk >> 32) >= red_hi[g]) {
            atomicMax(&red[g], pk);
            atomicMax(&red_hi[g], (unsigned int)(pk >> 32));
        }
    }
#pragma unroll
    for (int j = 0; j < 4; ++j) {
        best_iou[b * AA + aidx[j]] = bi[j];
        best_idx[b * AA + aidx[j]] = (unsigned char)bix[j];
    }
    __syncthreads();
    if (t < GG) atomicMax(&packed[b * GG + t], red[t]);
}

// ---------------- K2: per-anchor pos/bce/loc + hist level 0 + (b==15) mean-iou ----------------
__global__ __launch_bounds__(256) void k_anchor(const float4* __restrict__ bbox,
                                                const float* __restrict__ conf,
                                                const float4* __restrict__ gt,
                                                const float* __restrict__ best_iou,
                                                const unsigned char* __restrict__ best_idx,
                                                const unsigned long long* __restrict__ packed,
                                                float* __restrict__ neg_bce,
                                                int* __restrict__ hist0,
                                                int* __restrict__ num_pos,
                                                float* __restrict__ loc_sum,
                                                float* __restrict__ posbce,
                                                int* __restrict__ pred_cnt,
                                                float* __restrict__ miou_s,
                                                int* __restrict__ miou_c) {
    const int b = blockIdx.y, t = threadIdx.x;
    const int a = blockIdx.x * 256 + t;
    __shared__ float4 gts[GG];
    __shared__ unsigned int fpos[GG];
    __shared__ int sh[256];
    __shared__ float sloc[4], spb[4];
    __shared__ int snp[4], spc[4];
    __shared__ float sms[4];
    __shared__ int smc[4];
    sh[t] = 0;
    if (t < GG) {
        gts[t] = gt[b * GG + t];
        fpos[t] = 0xFFFFFFFFu - (unsigned int)(packed[b * GG + t] & 0xFFFFFFFFull);
    }
    __syncthreads();
    const int idx = b * AA + a;
    float p = conf[idx];
    float biou = best_iou[idx];
    bool force = false;
#pragma unroll
    for (int g = 0; g < GG; ++g) force |= ((unsigned int)a == fpos[g]);
    bool pos = (biou > 0.5f) || force;
    float bce, nb;
    if (pos) { bce = -fmaxf(logf(p), -100.0f); nb = 0.0f; }
    else     { bce = -fmaxf(log1pf(-p), -100.0f); nb = bce; }
    neg_bce[idx] = nb;
    if (!pos) atomicAdd(&sh[__float_as_uint(nb) >> 24], 1);
    float loc = 0.0f;
    if (pos) {
        float4 bp = bbox[idx];
        float4 gb = gts[best_idx[idx]];
        float pcx = __fmul_rn(__fadd_rn(bp.x, bp.z), 0.5f);
        float pcy = __fmul_rn(__fadd_rn(bp.y, bp.w), 0.5f);
        float pw = __fsub_rn(bp.z, bp.x), ph = __fsub_rn(bp.w, bp.y);
        float gcx = __fmul_rn(__fadd_rn(gb.x, gb.z), 0.5f);
        float gcy = __fmul_rn(__fadd_rn(gb.y, gb.w), 0.5f);
        float gw = __fsub_rn(gb.z, gb.x), gh = __fsub_rn(gb.w, gb.y);
        loc = __fadd_rn(__fadd_rn(__fadd_rn(sl1(pcx, gcx), sl1(pcy, gcy)), sl1(pw, gw)), sl1(ph, gh));
    }
    int np_ = pos ? 1 : 0;
    int pc = (p > 0.5f) ? 1 : 0;
    float pb = pos ? bce : 0.0f;
#pragma unroll
    for (int off = 32; off; off >>= 1) {
        loc += __shfl_xor(loc, off, 64);
        pb  += __shfl_xor(pb, off, 64);
        np_ += __shfl_xor(np_, off, 64);
        pc  += __shfl_xor(pc, off, 64);
    }
    const int lane = t & 63, wv = t >> 6;
    if (lane == 0) { sloc[wv] = loc; spb[wv] = pb; snp[wv] = np_; spc[wv] = pc; }
    // mean-iou over last image (bgi > 0 mask)
    if (b == BB - 1) {
        float ms = (biou > 0.0f) ? biou : 0.0f;
        int mc = (biou > 0.0f) ? 1 : 0;
#pragma unroll
        for (int off = 32; off; off >>= 1) {
            ms += __shfl_xor(ms, off, 64);
            mc += __shfl_xor(mc, off, 64);
        }
        if (lane == 0) { sms[wv] = ms; smc[wv] = mc; }
    }
    __syncthreads();
    if (t == 0) {
        float L = sloc[0] + sloc[1] + sloc[2] + sloc[3];
        float P = spb[0] + spb[1] + spb[2] + spb[3];
        int   N = snp[0] + snp[1] + snp[2] + snp[3];
        int   C = spc[0] + spc[1] + spc[2] + spc[3];
        if (L != 0.0f) atomicAdd(&loc_sum[b], L);
        if (P != 0.0f) atomicAdd(&posbce[b], P);
        if (N) atomicAdd(&num_pos[b], N);
        if (C) atomicAdd(&pred_cnt[b], C);
        if (b == BB - 1) {
            float S = sms[0] + sms[1] + sms[2] + sms[3];
            int   M = smc[0] + smc[1] + smc[2] + smc[3];
            if (S != 0.0f) atomicAdd(miou_s, S);
            if (M) atomicAdd(miou_c, M);
        }
    }
    if (sh[t]) atomicAdd(&hist0[b * 256 + t], sh[t]);
}

// ---------------- radix-select scan of one 8-bit level (256 threads) ----------------
__device__ __forceinline__ void scan_level(const int* __restrict__ histL, int t,
                                           int* ss, int* sres,
                                           unsigned int* prefix, int* k, int shift) {
    int kk = *k;
    ss[t] = histL[t];
    __syncthreads();
#pragma unroll
    for (int off = 1; off < 256; off <<= 1) {
        int v = (t + off < 256) ? ss[t + off] : 0;
        __syncthreads();
        ss[t] += v;
        __syncthreads();
    }
    if (ss[t] >= kk && (t == 255 || ss[t + 1] < kk)) {
        sres[0] = t;
        sres[1] = (t == 255) ? kk : (kk - ss[t + 1]);
    }
    __syncthreads();
    *prefix |= ((unsigned int)sres[0]) << shift;
    *k = sres[1];
    __syncthreads();
}

// ---------------- K3: radix histogram passes 1..3 ----------------
__global__ __launch_bounds__(256) void k_hist(const float* __restrict__ neg_bce,
                                              int* __restrict__ hist,
                                              const int* __restrict__ num_pos,
                                              int pass) {
    const int b = blockIdx.y, t = threadIdx.x;
    __shared__ int ss[256];
    __shared__ int sres[2];
    __shared__ int sh[256];
    int np_ = num_pos[b];
    int k = min(3 * np_, AA - np_);
    if (k <= 0) return;
    unsigned int prefix = 0;
    for (int L = 0; L < pass; ++L)
        scan_level(&hist[(L * BB + b) * 256], t, ss, sres, &prefix, &k, 24 - 8 * L);
    sh[t] = 0;
    __syncthreads();
    const unsigned int pmask = 0xFFFFFFFFu << (32 - 8 * pass);
    const int shift = 24 - 8 * pass;
    for (int a = blockIdx.x * 256 + t; a < AA; a += gridDim.x * 256) {
        unsigned int bits = __float_as_uint(neg_bce[b * AA + a]);
        if ((bits & pmask) == prefix) atomicAdd(&sh[(bits >> shift) & 0xFFu], 1);
    }
    __syncthreads();
    if (sh[t]) atomicAdd(&hist[(pass * BB + b) * 256 + t], sh[t]);
}

// ---------------- K4: sum of values strictly greater than kth value; export vk ----------------
__global__ __launch_bounds__(256) void k_topk(const float* __restrict__ neg_bce,
                                              const int* __restrict__ hist,
                                              const int* __restrict__ num_pos,
                                              float* __restrict__ negsum,
                                              int* __restrict__ ngt,
                                              float* __restrict__ vk_arr) {
    const int b = blockIdx.y, t = threadIdx.x;
    __shared__ int ss[256];
    __shared__ int sres[2];
    __shared__ float sfs[4];
    __shared__ int sfc[4];
    int np_ = num_pos[b];
    int k = min(3 * np_, AA - np_);
    if (k <= 0) return;
    unsigned int prefix = 0;
    for (int L = 0; L < 4; ++L)
        scan_level(&hist[(L * BB + b) * 256], t, ss, sres, &prefix, &k, 24 - 8 * L);
    const float vk = __uint_as_float(prefix);
    if (blockIdx.x == 0 && t == 0) vk_arr[b] = vk;
    float s = 0.0f; int c = 0;
    for (int a = blockIdx.x * 256 + t; a < AA; a += gridDim.x * 256) {
        float v = neg_bce[b * AA + a];
        if (v > vk) { s += v; c++; }
    }
#pragma unroll
    for (int off = 32; off; off >>= 1) { s += __shfl_xor(s, off, 64); c += __shfl_xor(c, off, 64); }
    const int lane = t & 63, wv = t >> 6;
    if (lane == 0) { sfs[wv] = s; sfc[wv] = c; }
    __syncthreads();
    if (t == 0) {
        float S = sfs[0] + sfs[1] + sfs[2] + sfs[3];
        int   C = sfc[0] + sfc[1] + sfc[2] + sfc[3];
        if (S != 0.0f) atomicAdd(&negsum[b], S);
        if (C) atomicAdd(&ngt[b], C);
    }
}

// ---------------- K5: trivial final combine ----------------
__global__ void k_final(const int* __restrict__ num_pos,
                        const float* __restrict__ loc_sum,
                        const float* __restrict__ posbce,
                        const float* __restrict__ negsum,
                        const int* __restrict__ ngt,
                        const float* __restrict__ vk_arr,
                        const int* __restrict__ pred_cnt,
                        const float* __restrict__ miou_s,
                        const int* __restrict__ miou_c,
                        float* __restrict__ out) {
    if (threadIdx.x == 0) {
        int npos_t = 0; float loc_t = 0.0f, conf_t = 0.0f, cnt_t = 0.0f;
        for (int b = 0; b < BB; ++b) {
            int np_ = num_pos[b];
            int k0 = min(3 * np_, AA - np_);
            float add = posbce[b] + negsum[b];
            if (k0 > 0) add += (float)(k0 - ngt[b]) * vk_arr[b];
            conf_t += add;
            npos_t += np_;
            loc_t += loc_sum[b];
            float diff = fabsf((float)(pred_cnt[b] - GG));
            cnt_t += (diff <= 3.0f) ? diff * 0.2f
                                    : 0.6f + 0.2f * logf(fmaxf(diff - 2.0f, 1.0f));
        }
        float total_count = cnt_t / (float)BB;
        float npos = (float)max(1, npos_t);
        float total_loc = loc_t / npos;
        float total_conf = conf_t / npos;
        int C = *miou_c;
        float mean_iou = (C > 0) ? (*miou_s / (float)max(C, 1)) : 0.1f;
        float q = fminf(fmaxf(1.0f - mean_iou, 0.1f), 0.9f);
        float dyn = 1.0f + q;
        out[0] = dyn * total_loc + total_conf + 0.2f * total_count;
        out[1] = total_conf;
        out[2] = total_loc;
        out[3] = total_count;
        out[4] = mean_iou;
    }
}

extern "C" void kernel_launch(void* const* d_in, const int* in_sizes, int n_in,
                              void* d_out, int out_size, void* d_ws, size_t ws_size,
                              hipStream_t stream) {
    (void)in_sizes; (void)n_in; (void)out_size; (void)ws_size;
    const float* bbox    = (const float*)d_in[0];
    const float* conf    = (const float*)d_in[1];
    const float* anchors = (const float*)d_in[2];
    const float* gt      = (const float*)d_in[3];
    char* ws = (char*)d_ws;
    unsigned long long* packed = (unsigned long long*)(ws + OFF_PACKED);
    int*   hist     = (int*)(ws + OFF_HIST);
    int*   num_pos  = (int*)(ws + OFF_NUMPOS);
    float* loc_sum  = (float*)(ws + OFF_LOCSUM);
    float* posbce   = (float*)(ws + OFF_POSBCE);
    int*   pred_cnt = (int*)(ws + OFF_PREDCNT);
    float* negsum   = (float*)(ws + OFF_NEGSUM);
    int*   ngt      = (int*)(ws + OFF_NGT);
    float* miou_s   = (float*)(ws + OFF_MIOU_S);
    int*   miou_c   = (int*)(ws + OFF_MIOU_C);
    float* vk_arr   = (float*)(ws + OFF_VK);
    float* best_iou = (float*)(ws + OFF_BESTIOU);
    unsigned char* best_idx = (unsigned char*)(ws + OFF_BESTIDX);
    float* neg_bce  = (float*)(ws + OFF_NEGBCE);

    hipMemsetAsync(d_ws, 0, MEMSET_BYTES, stream);
    k_iou<<<dim3(64, BB), 256, 0, stream>>>((const float4*)anchors, (const float4*)gt,
                                            best_iou, best_idx, packed);
    k_anchor<<<dim3(256, BB), 256, 0, stream>>>((const float4*)bbox, conf, (const float4*)gt,
                                                best_iou, best_idx, packed, neg_bce,
                                                hist, num_pos, loc_sum, posbce, pred_cnt,
                                                miou_s, miou_c);
    for (int pass = 1; pass <= 3; ++pass)
        k_hist<<<dim3(64, BB), 256, 0, stream>>>(neg_bce, hist, num_pos, pass);
    k_topk<<<dim3(64, BB), 256, 0, stream>>>(neg_bce, hist, num_pos, negsum, ngt, vk_arr);
    k_final<<<1, 64, 0, stream>>>(num_pos, loc_sum, posbce, negsum, ngt, vk_arr,
                                  pred_cnt, miou_s, miou_c, (float*)d_out);
}

// Round 3
// 235.055 us; speedup vs baseline: 1.9703x; 1.9703x over previous
//
#include <hip/hip_runtime.h>
#include <math.h>

#define BB 16
#define AA 65536
#define GG 32

// workspace layout (bytes)
#define OFF_PACKED   0            // u64[BB*GG]                      4096
#define OFF_HIST     4096         // int[4][BB][256]                 65536
#define OFF_NUMPOS   69632        // int[BB]
#define OFF_LOCSUM   69696        // float[BB]
#define OFF_POSBCE   69760        // float[BB]
#define OFF_PREDCNT  69824        // int[BB]
#define OFF_NEGSUM   69888        // float[BB]
#define OFF_NGT      69952        // int[BB]
#define OFF_MIOU_S   70016        // float
#define OFF_MIOU_C   70020        // int
#define OFF_VK       70080        // float[BB]
#define MEMSET_BYTES 71680        // zero [0, 70KiB)
#define OFF_NEGBCE   2097152      // float[BB*AA]                    4 MiB

__device__ __forceinline__ float iou_exact(float ax, float ay, float az, float aw,
                                           float area_a,
                                           float gx, float gy, float gz, float gw,
                                           float area_g) {
    float lx = fmaxf(ax, gx), ly = fmaxf(ay, gy);
    float rx = fminf(az, gz), ry = fminf(aw, gw);
    float w = fmaxf(__fsub_rn(rx, lx), 0.0f);
    float h = fmaxf(__fsub_rn(ry, ly), 0.0f);
    float inter = __fmul_rn(w, h);
    float uni = __fsub_rn(__fadd_rn(area_a, area_g), inter);
    return __fdiv_rn(inter, __fadd_rn(uni, 1e-6f));
}

__device__ __forceinline__ float sl1(float x, float y) {
    float d = fabsf(__fsub_rn(x, y));
    return (d < 1.0f) ? __fmul_rn(__fmul_rn(0.5f, d), d) : __fsub_rn(d, 0.5f);
}

// ---------------- K1: per-gt argmax over anchors ----------------
// grid (32, BB): blockIdx.x = half(1b) * 16 + ggroup(4b); 2 gts per block, half the anchors.
__global__ __launch_bounds__(256) void k_gt(const float4* __restrict__ anchors,
                                            const float4* __restrict__ gt,
                                            unsigned long long* __restrict__ packed) {
    const int b = blockIdx.y;
    const int gbase = (blockIdx.x & 15) * 2;
    const int half = blockIdx.x >> 4;
    const int t = threadIdx.x;
    float4 g0 = gt[b * GG + gbase];
    float4 g1 = gt[b * GG + gbase + 1];
    float ag0 = __fmul_rn(__fsub_rn(g0.z, g0.x), __fsub_rn(g0.w, g0.y));
    float ag1 = __fmul_rn(__fsub_rn(g1.z, g1.x), __fsub_rn(g1.w, g1.y));
    unsigned long long p0 = 0ull, p1 = 0ull;
    const int base = half * (AA / 2);
#pragma unroll 2
    for (int i = 0; i < AA / 2 / 256; ++i) {
        int a = base + i * 256 + t;
        float4 an = anchors[a];
        float aa = __fmul_rn(__fsub_rn(an.z, an.x), __fsub_rn(an.w, an.y));
        float i0 = iou_exact(an.x, an.y, an.z, an.w, aa, g0.x, g0.y, g0.z, g0.w, ag0);
        float i1 = iou_exact(an.x, an.y, an.z, an.w, aa, g1.x, g1.y, g1.z, g1.w, ag1);
        unsigned long long q0 = ((unsigned long long)__float_as_uint(i0) << 32)
                              | (unsigned long long)(0xFFFFFFFFu - (unsigned)a);
        unsigned long long q1 = ((unsigned long long)__float_as_uint(i1) << 32)
                              | (unsigned long long)(0xFFFFFFFFu - (unsigned)a);
        if (q0 > p0) p0 = q0;
        if (q1 > p1) p1 = q1;
    }
#pragma unroll
    for (int off = 32; off; off >>= 1) {
        unsigned long long q0 = __shfl_xor(p0, off, 64); if (q0 > p0) p0 = q0;
        unsigned long long q1 = __shfl_xor(p1, off, 64); if (q1 > p1) p1 = q1;
    }
    __shared__ unsigned long long red[2][4];
    const int lane = t & 63, wv = t >> 6;
    if (lane == 0) { red[0][wv] = p0; red[1][wv] = p1; }
    __syncthreads();
    if (t == 0) {
        unsigned long long P0 = red[0][0], P1 = red[1][0];
#pragma unroll
        for (int w = 1; w < 4; ++w) {
            if (red[0][w] > P0) P0 = red[0][w];
            if (red[1][w] > P1) P1 = red[1][w];
        }
        atomicMax(&packed[b * GG + gbase], P0);
        atomicMax(&packed[b * GG + gbase + 1], P1);
    }
}

// ---------------- K2: fused per-anchor IoU + pos/bce/loc + hist0 + (b==15) mean-iou ----------------
__global__ __launch_bounds__(256) void k_anchor(const float4* __restrict__ bbox,
                                                const float* __restrict__ conf,
                                                const float4* __restrict__ anchors,
                                                const float4* __restrict__ gt,
                                                const unsigned long long* __restrict__ packed,
                                                float* __restrict__ neg_bce,
                                                int* __restrict__ hist0,
                                                int* __restrict__ num_pos,
                                                float* __restrict__ loc_sum,
                                                float* __restrict__ posbce,
                                                int* __restrict__ pred_cnt,
                                                float* __restrict__ miou_s,
                                                int* __restrict__ miou_c) {
    const int b = blockIdx.y, t = threadIdx.x;
    const int a = blockIdx.x * 256 + t;
    __shared__ float4 gts[GG];
    __shared__ float areag[GG];
    __shared__ unsigned int fpos[GG];
    __shared__ int sh[256];
    __shared__ float sloc[4], spb[4];
    __shared__ int snp[4], spc[4];
    __shared__ float sms[4];
    __shared__ int smc[4];
    sh[t] = 0;
    if (t < GG) {
        float4 g4 = gt[b * GG + t];
        gts[t] = g4;
        areag[t] = __fmul_rn(__fsub_rn(g4.z, g4.x), __fsub_rn(g4.w, g4.y));
        fpos[t] = 0xFFFFFFFFu - (unsigned int)(packed[b * GG + t] & 0xFFFFFFFFull);
    }
    __syncthreads();
    const int idx = b * AA + a;
    float4 an = anchors[a];
    float aa = __fmul_rn(__fsub_rn(an.z, an.x), __fsub_rn(an.w, an.y));
    float biou = -1.0f; int bidx = 0;
#pragma unroll 4
    for (int g = 0; g < GG; ++g) {
        float4 gb = gts[g];
        float iou = iou_exact(an.x, an.y, an.z, an.w, aa, gb.x, gb.y, gb.z, gb.w, areag[g]);
        if (iou > biou) { biou = iou; bidx = g; }
    }
    bool force = false;
#pragma unroll
    for (int g = 0; g < GG; ++g) force |= ((unsigned int)a == fpos[g]);
    bool pos = (biou > 0.5f) || force;
    float p = conf[idx];
    float bce, nb;
    if (pos) { bce = -fmaxf(logf(p), -100.0f); nb = 0.0f; }
    else     { bce = -fmaxf(log1pf(-p), -100.0f); nb = bce; }
    neg_bce[idx] = nb;
    if (!pos) atomicAdd(&sh[__float_as_uint(nb) >> 24], 1);
    float loc = 0.0f;
    if (pos) {
        float4 bp = bbox[idx];
        float4 gb = gts[bidx];
        float pcx = __fmul_rn(__fadd_rn(bp.x, bp.z), 0.5f);
        float pcy = __fmul_rn(__fadd_rn(bp.y, bp.w), 0.5f);
        float pw = __fsub_rn(bp.z, bp.x), ph = __fsub_rn(bp.w, bp.y);
        float gcx = __fmul_rn(__fadd_rn(gb.x, gb.z), 0.5f);
        float gcy = __fmul_rn(__fadd_rn(gb.y, gb.w), 0.5f);
        float gw = __fsub_rn(gb.z, gb.x), gh = __fsub_rn(gb.w, gb.y);
        loc = __fadd_rn(__fadd_rn(__fadd_rn(sl1(pcx, gcx), sl1(pcy, gcy)), sl1(pw, gw)), sl1(ph, gh));
    }
    int np_ = pos ? 1 : 0;
    int pc = (p > 0.5f) ? 1 : 0;
    float pb = pos ? bce : 0.0f;
#pragma unroll
    for (int off = 32; off; off >>= 1) {
        loc += __shfl_xor(loc, off, 64);
        pb  += __shfl_xor(pb, off, 64);
        np_ += __shfl_xor(np_, off, 64);
        pc  += __shfl_xor(pc, off, 64);
    }
    const int lane = t & 63, wv = t >> 6;
    if (lane == 0) { sloc[wv] = loc; spb[wv] = pb; snp[wv] = np_; spc[wv] = pc; }
    if (b == BB - 1) {
        float ms = (biou > 0.0f) ? biou : 0.0f;
        int mc = (biou > 0.0f) ? 1 : 0;
#pragma unroll
        for (int off = 32; off; off >>= 1) {
            ms += __shfl_xor(ms, off, 64);
            mc += __shfl_xor(mc, off, 64);
        }
        if (lane == 0) { sms[wv] = ms; smc[wv] = mc; }
    }
    __syncthreads();
    if (t == 0) {
        float L = sloc[0] + sloc[1] + sloc[2] + sloc[3];
        float P = spb[0] + spb[1] + spb[2] + spb[3];
        int   N = snp[0] + snp[1] + snp[2] + snp[3];
        int   C = spc[0] + spc[1] + spc[2] + spc[3];
        if (L != 0.0f) atomicAdd(&loc_sum[b], L);
        if (P != 0.0f) atomicAdd(&posbce[b], P);
        if (N) atomicAdd(&num_pos[b], N);
        if (C) atomicAdd(&pred_cnt[b], C);
        if (b == BB - 1) {
            float S = sms[0] + sms[1] + sms[2] + sms[3];
            int   M = smc[0] + smc[1] + smc[2] + smc[3];
            if (S != 0.0f) atomicAdd(miou_s, S);
            if (M) atomicAdd(miou_c, M);
        }
    }
    if (sh[t]) atomicAdd(&hist0[b * 256 + t], sh[t]);
}

// ---------------- radix-select scan of one 8-bit level (256 threads) ----------------
__device__ __forceinline__ void scan_level(const int* __restrict__ histL, int t,
                                           int* ss, int* sres,
                                           unsigned int* prefix, int* k, int shift) {
    int kk = *k;
    ss[t] = histL[t];
    __syncthreads();
#pragma unroll
    for (int off = 1; off < 256; off <<= 1) {
        int v = (t + off < 256) ? ss[t + off] : 0;
        __syncthreads();
        ss[t] += v;
        __syncthreads();
    }
    if (ss[t] >= kk && (t == 255 || ss[t + 1] < kk)) {
        sres[0] = t;
        sres[1] = (t == 255) ? kk : (kk - ss[t + 1]);
    }
    __syncthreads();
    *prefix |= ((unsigned int)sres[0]) << shift;
    *k = sres[1];
    __syncthreads();
}

// ---------------- K3: radix histogram passes 1..3 ----------------
__global__ __launch_bounds__(256) void k_hist(const float* __restrict__ neg_bce,
                                              int* __restrict__ hist,
                                              const int* __restrict__ num_pos,
                                              int pass) {
    const int b = blockIdx.y, t = threadIdx.x;
    __shared__ int ss[256];
    __shared__ int sres[2];
    __shared__ int sh[256];
    int np_ = num_pos[b];
    int k = min(3 * np_, AA - np_);
    if (k <= 0) return;
    unsigned int prefix = 0;
    for (int L = 0; L < pass; ++L)
        scan_level(&hist[(L * BB + b) * 256], t, ss, sres, &prefix, &k, 24 - 8 * L);
    sh[t] = 0;
    __syncthreads();
    const unsigned int pmask = 0xFFFFFFFFu << (32 - 8 * pass);
    const int shift = 24 - 8 * pass;
    for (int a = blockIdx.x * 256 + t; a < AA; a += gridDim.x * 256) {
        unsigned int bits = __float_as_uint(neg_bce[b * AA + a]);
        if ((bits & pmask) == prefix) atomicAdd(&sh[(bits >> shift) & 0xFFu], 1);
    }
    __syncthreads();
    if (sh[t]) atomicAdd(&hist[(pass * BB + b) * 256 + t], sh[t]);
}

// ---------------- K4: sum of values strictly greater than kth value; export vk ----------------
__global__ __launch_bounds__(256) void k_topk(const float* __restrict__ neg_bce,
                                              const int* __restrict__ hist,
                                              const int* __restrict__ num_pos,
                                              float* __restrict__ negsum,
                                              int* __restrict__ ngt,
                                              float* __restrict__ vk_arr) {
    const int b = blockIdx.y, t = threadIdx.x;
    __shared__ int ss[256];
    __shared__ int sres[2];
    __shared__ float sfs[4];
    __shared__ int sfc[4];
    int np_ = num_pos[b];
    int k = min(3 * np_, AA - np_);
    if (k <= 0) return;
    unsigned int prefix = 0;
    for (int L = 0; L < 4; ++L)
        scan_level(&hist[(L * BB + b) * 256], t, ss, sres, &prefix, &k, 24 - 8 * L);
    const float vk = __uint_as_float(prefix);
    if (blockIdx.x == 0 && t == 0) vk_arr[b] = vk;
    float s = 0.0f; int c = 0;
    for (int a = blockIdx.x * 256 + t; a < AA; a += gridDim.x * 256) {
        float v = neg_bce[b * AA + a];
        if (v > vk) { s += v; c++; }
    }
#pragma unroll
    for (int off = 32; off; off >>= 1) { s += __shfl_xor(s, off, 64); c += __shfl_xor(c, off, 64); }
    const int lane = t & 63, wv = t >> 6;
    if (lane == 0) { sfs[wv] = s; sfc[wv] = c; }
    __syncthreads();
    if (t == 0) {
        float S = sfs[0] + sfs[1] + sfs[2] + sfs[3];
        int   C = sfc[0] + sfc[1] + sfc[2] + sfc[3];
        if (S != 0.0f) atomicAdd(&negsum[b], S);
        if (C) atomicAdd(&ngt[b], C);
    }
}

// ---------------- K5: trivial final combine ----------------
__global__ void k_final(const int* __restrict__ num_pos,
                        const float* __restrict__ loc_sum,
                        const float* __restrict__ posbce,
                        const float* __restrict__ negsum,
                        const int* __restrict__ ngt,
                        const float* __restrict__ vk_arr,
                        const int* __restrict__ pred_cnt,
                        const float* __restrict__ miou_s,
                        const int* __restrict__ miou_c,
                        float* __restrict__ out) {
    if (threadIdx.x == 0) {
        int npos_t = 0; float loc_t = 0.0f, conf_t = 0.0f, cnt_t = 0.0f;
        for (int b = 0; b < BB; ++b) {
            int np_ = num_pos[b];
            int k0 = min(3 * np_, AA - np_);
            float add = posbce[b] + negsum[b];
            if (k0 > 0) add += (float)(k0 - ngt[b]) * vk_arr[b];
            conf_t += add;
            npos_t += np_;
            loc_t += loc_sum[b];
            float diff = fabsf((float)(pred_cnt[b] - GG));
            cnt_t += (diff <= 3.0f) ? diff * 0.2f
                                    : 0.6f + 0.2f * logf(fmaxf(diff - 2.0f, 1.0f));
        }
        float total_count = cnt_t / (float)BB;
        float npos = (float)max(1, npos_t);
        float total_loc = loc_t / npos;
        float total_conf = conf_t / npos;
        int C = *miou_c;
        float mean_iou = (C > 0) ? (*miou_s / (float)max(C, 1)) : 0.1f;
        float q = fminf(fmaxf(1.0f - mean_iou, 0.1f), 0.9f);
        float dyn = 1.0f + q;
        out[0] = dyn * total_loc + total_conf + 0.2f * total_count;
        out[1] = total_conf;
        out[2] = total_loc;
        out[3] = total_count;
        out[4] = mean_iou;
    }
}

extern "C" void kernel_launch(void* const* d_in, const int* in_sizes, int n_in,
                              void* d_out, int out_size, void* d_ws, size_t ws_size,
                              hipStream_t stream) {
    (void)in_sizes; (void)n_in; (void)out_size; (void)ws_size;
    const float* bbox    = (const float*)d_in[0];
    const float* conf    = (const float*)d_in[1];
    const float* anchors = (const float*)d_in[2];
    const float* gt      = (const float*)d_in[3];
    char* ws = (char*)d_ws;
    unsigned long long* packed = (unsigned long long*)(ws + OFF_PACKED);
    int*   hist     = (int*)(ws + OFF_HIST);
    int*   num_pos  = (int*)(ws + OFF_NUMPOS);
    float* loc_sum  = (float*)(ws + OFF_LOCSUM);
    float* posbce   = (float*)(ws + OFF_POSBCE);
    int*   pred_cnt = (int*)(ws + OFF_PREDCNT);
    float* negsum   = (float*)(ws + OFF_NEGSUM);
    int*   ngt      = (int*)(ws + OFF_NGT);
    float* miou_s   = (float*)(ws + OFF_MIOU_S);
    int*   miou_c   = (int*)(ws + OFF_MIOU_C);
    float* vk_arr   = (float*)(ws + OFF_VK);
    float* neg_bce  = (float*)(ws + OFF_NEGBCE);

    hipMemsetAsync(d_ws, 0, MEMSET_BYTES, stream);
    k_gt<<<dim3(32, BB), 256, 0, stream>>>((const float4*)anchors, (const float4*)gt, packed);
    k_anchor<<<dim3(256, BB), 256, 0, stream>>>((const float4*)bbox, conf,
                                                (const float4*)anchors, (const float4*)gt,
                                                packed, neg_bce,
                                                hist, num_pos, loc_sum, posbce, pred_cnt,
                                                miou_s, miou_c);
    for (int pass = 1; pass <= 3; ++pass)
        k_hist<<<dim3(64, BB), 256, 0, stream>>>(neg_bce, hist, num_pos, pass);
    k_topk<<<dim3(64, BB), 256, 0, stream>>>(neg_bce, hist, num_pos, negsum, ngt, vk_arr);
    k_final<<<1, 64, 0, stream>>>(num_pos, loc_sum, posbce, negsum, ngt, vk_arr,
                                  pred_cnt, miou_s, miou_c, (float*)d_out);
}

// Round 6
// 165.154 us; speedup vs baseline: 2.8043x; 1.4233x over previous
//
#include <hip/hip_runtime.h>
#include <math.h>

#define BB 16
#define AA 65536
#define GG 32

// workspace layout (bytes)
#define OFF_PACKED   0            // u64[BB*GG]                      4096
#define OFF_HIST     4096         // int[4][BB][256]                 65536
#define OFF_NUMPOS   69632        // int[BB]
#define OFF_LOCSUM   69696        // float[BB]
#define OFF_POSBCE   69760        // float[BB]
#define OFF_PREDCNT  69824        // int[BB]
#define OFF_NEGSUM   69888        // float[BB]
#define OFF_NGT      69952        // int[BB]
#define OFF_MIOU_S   70016        // float
#define OFF_MIOU_C   70020        // int
#define OFF_VK       70080        // float[BB]
#define MEMSET_BYTES 71680        // zero [0, 70KiB)
#define OFF_NEGBCE   2097152      // float[BB*AA]                    4 MiB

__device__ __forceinline__ float iou_exact(float ax, float ay, float az, float aw,
                                           float area_a,
                                           float gx, float gy, float gz, float gw,
                                           float area_g) {
    float lx = fmaxf(ax, gx), ly = fmaxf(ay, gy);
    float rx = fminf(az, gz), ry = fminf(aw, gw);
    float w = fmaxf(__fsub_rn(rx, lx), 0.0f);
    float h = fmaxf(__fsub_rn(ry, ly), 0.0f);
    float inter = __fmul_rn(w, h);
    float uni = __fsub_rn(__fadd_rn(area_a, area_g), inter);
    return __fdiv_rn(inter, __fadd_rn(uni, 1e-6f));
}

__device__ __forceinline__ float sl1(float x, float y) {
    float d = fabsf(__fsub_rn(x, y));
    return (d < 1.0f) ? __fmul_rn(__fmul_rn(0.5f, d), d) : __fsub_rn(d, 0.5f);
}

__device__ __forceinline__ float loc_term(float4 bp, float4 gb) {
    float pcx = __fmul_rn(__fadd_rn(bp.x, bp.z), 0.5f);
    float pcy = __fmul_rn(__fadd_rn(bp.y, bp.w), 0.5f);
    float pw = __fsub_rn(bp.z, bp.x), ph = __fsub_rn(bp.w, bp.y);
    float gcx = __fmul_rn(__fadd_rn(gb.x, gb.z), 0.5f);
    float gcy = __fmul_rn(__fadd_rn(gb.y, gb.w), 0.5f);
    float gw = __fsub_rn(gb.z, gb.x), gh = __fsub_rn(gb.w, gb.y);
    return __fadd_rn(__fadd_rn(__fadd_rn(sl1(pcx, gcx), sl1(pcy, gcy)), sl1(pw, gw)), sl1(ph, gh));
}

// ---------------- K1: fused anchor pass — per-anchor argmax + per-gt argmax + bce/loc/hist0 ----------------
// grid (64, BB), 256 threads, 4 anchors per thread (aidx = base + j*256 + t).
__global__ __launch_bounds__(256) void k_main(const float4* __restrict__ bbox,
                                              const float* __restrict__ conf,
                                              const float4* __restrict__ anchors,
                                              const float4* __restrict__ gt,
                                              unsigned long long* __restrict__ packed,
                                              float* __restrict__ neg_bce,
                                              int* __restrict__ hist0,
                                              int* __restrict__ num_pos,
                                              float* __restrict__ loc_sum,
                                              float* __restrict__ posbce,
                                              int* __restrict__ pred_cnt,
                                              float* __restrict__ miou_s,
                                              int* __restrict__ miou_c) {
    const int b = blockIdx.y, t = threadIdx.x;
    const int base = blockIdx.x * 1024;
    __shared__ unsigned long long red[4][GG];
    __shared__ int sh[256];
    __shared__ float sloc[4], spb[4], sms[4];
    __shared__ int snp[4], spc[4], smc[4];
    sh[t] = 0;
    float4 an[4]; float aa[4]; float bi[4]; int bix[4]; int aidx[4];
#pragma unroll
    for (int j = 0; j < 4; ++j) {
        aidx[j] = base + j * 256 + t;
        an[j] = anchors[aidx[j]];
        aa[j] = __fmul_rn(__fsub_rn(an[j].z, an[j].x), __fsub_rn(an[j].w, an[j].y));
        bi[j] = -1.0f; bix[j] = 0;
    }
    __syncthreads();
    const int lane = t & 63, wv = t >> 6;
    // two gts per iteration: interleaved u64 butterflies overlap their bpermute latency
    for (int g = 0; g < GG; g += 2) {
        float4 g0 = gt[b * GG + g];
        float4 g1 = gt[b * GG + g + 1];
        float ag0 = __fmul_rn(__fsub_rn(g0.z, g0.x), __fsub_rn(g0.w, g0.y));
        float ag1 = __fmul_rn(__fsub_rn(g1.z, g1.x), __fsub_rn(g1.w, g1.y));
        unsigned long long pk0 = 0ull, pk1 = 0ull;
#pragma unroll
        for (int j = 0; j < 4; ++j) {
            float i0 = iou_exact(an[j].x, an[j].y, an[j].z, an[j].w, aa[j],
                                 g0.x, g0.y, g0.z, g0.w, ag0);
            float i1 = iou_exact(an[j].x, an[j].y, an[j].z, an[j].w, aa[j],
                                 g1.x, g1.y, g1.z, g1.w, ag1);
            if (i0 > bi[j]) { bi[j] = i0; bix[j] = g; }       // ascending g: strict > keeps first
            if (i1 > bi[j]) { bi[j] = i1; bix[j] = g + 1; }
            unsigned long long p0 = ((unsigned long long)__float_as_uint(i0) << 32)
                                  | (unsigned long long)(0xFFFFFFFFu - (unsigned)aidx[j]);
            unsigned long long p1 = ((unsigned long long)__float_as_uint(i1) << 32)
                                  | (unsigned long long)(0xFFFFFFFFu - (unsigned)aidx[j]);
            if (p0 > pk0) pk0 = p0;
            if (p1 > pk1) pk1 = p1;
        }
#pragma unroll
        for (int off = 32; off; off >>= 1) {
            unsigned long long q0 = __shfl_xor(pk0, off, 64);
            unsigned long long q1 = __shfl_xor(pk1, off, 64);
            if (q0 > pk0) pk0 = q0;
            if (q1 > pk1) pk1 = q1;
        }
        if (lane == 0) { red[wv][g] = pk0; red[wv][g + 1] = pk1; }
    }
    // per-anchor epilogue (pos here EXCLUDES force — fixed by k_force)
    float loc = 0.0f, pb = 0.0f, ms = 0.0f;
    int np_ = 0, pc = 0, mc = 0;
#pragma unroll
    for (int j = 0; j < 4; ++j) {
        const int idx = b * AA + aidx[j];
        float p = conf[idx];
        bool pos = bi[j] > 0.5f;
        float bce, nb;
        if (pos) { bce = -fmaxf(logf(p), -100.0f); nb = 0.0f; }
        else     { bce = -fmaxf(log1pf(-p), -100.0f); nb = bce; }
        neg_bce[idx] = nb;
        if (!pos) atomicAdd(&sh[__float_as_uint(nb) >> 24], 1);
        if (pos) {
            loc += loc_term(bbox[idx], gt[b * GG + bix[j]]);
            pb += bce;
            np_++;
        }
        pc += (p > 0.5f) ? 1 : 0;
        if (b == BB - 1 && bi[j] > 0.0f) { ms += bi[j]; mc++; }
    }
#pragma unroll
    for (int off = 32; off; off >>= 1) {
        loc += __shfl_xor(loc, off, 64);
        pb  += __shfl_xor(pb, off, 64);
        np_ += __shfl_xor(np_, off, 64);
        pc  += __shfl_xor(pc, off, 64);
        if (b == BB - 1) { ms += __shfl_xor(ms, off, 64); mc += __shfl_xor(mc, off, 64); }
    }
    if (lane == 0) {
        sloc[wv] = loc; spb[wv] = pb; snp[wv] = np_; spc[wv] = pc;
        sms[wv] = ms; smc[wv] = mc;
    }
    __syncthreads();
    if (t == 0) {
        float L = sloc[0] + sloc[1] + sloc[2] + sloc[3];
        float P = spb[0] + spb[1] + spb[2] + spb[3];
        int   N = snp[0] + snp[1] + snp[2] + snp[3];
        int   C = spc[0] + spc[1] + spc[2] + spc[3];
        if (L != 0.0f) atomicAdd(&loc_sum[b], L);
        if (P != 0.0f) atomicAdd(&posbce[b], P);
        if (N) atomicAdd(&num_pos[b], N);
        if (C) atomicAdd(&pred_cnt[b], C);
        if (b == BB - 1) {
            float S = sms[0] + sms[1] + sms[2] + sms[3];
            int   M = smc[0] + smc[1] + smc[2] + smc[3];
            if (S != 0.0f) atomicAdd(miou_s, S);
            if (M) atomicAdd(miou_c, M);
        }
    }
    if (t < GG) {
        unsigned long long p = red[0][t];
#pragma unroll
        for (int w = 1; w < 4; ++w) if (red[w][t] > p) p = red[w][t];
        atomicMax(&packed[b * GG + t], p);
    }
    if (sh[t]) atomicAdd(&hist0[b * 256 + t], sh[t]);
}

// ---------------- K2: correction for forced positives (per-gt best anchors) ----------------
// 1 block, 512 threads: thread = (image b = t>>5, gt g = t&31).
__global__ __launch_bounds__(512) void k_force(const float4* __restrict__ bbox,
                                               const float* __restrict__ conf,
                                               const float4* __restrict__ anchors,
                                               const float4* __restrict__ gt,
                                               const unsigned long long* __restrict__ packed,
                                               float* __restrict__ neg_bce,
                                               int* __restrict__ hist0,
                                               int* __restrict__ num_pos,
                                               float* __restrict__ loc_sum,
                                               float* __restrict__ posbce) {
    const int t = threadIdx.x;
    const int b = t >> 5, g = t & 31;
    __shared__ unsigned int win[BB][GG];
    unsigned int a = 0xFFFFFFFFu - (unsigned int)(packed[b * GG + g] & 0xFFFFFFFFull);
    win[b][g] = a;
    __syncthreads();
    bool dup = false;
    for (int gp = 0; gp < g; ++gp) dup |= (win[b][gp] == a);
    if (dup) return;
    // recompute this anchor's per-anchor argmax (bit-identical sequence to k_main)
    float4 an = anchors[a];
    float aa = __fmul_rn(__fsub_rn(an.z, an.x), __fsub_rn(an.w, an.y));
    float bi = -1.0f; int bix = 0;
    for (int gg = 0; gg < GG; ++gg) {
        float4 gv = gt[b * GG + gg];
        float ag = __fmul_rn(__fsub_rn(gv.z, gv.x), __fsub_rn(gv.w, gv.y));
        float iou = iou_exact(an.x, an.y, an.z, an.w, aa, gv.x, gv.y, gv.z, gv.w, ag);
        if (iou > bi) { bi = iou; bix = gg; }
    }
    if (bi > 0.5f) return;  // already counted as positive in k_main
    const int idx = b * AA + a;
    float p = conf[idx];
    float nb = -fmaxf(log1pf(-p), -100.0f);
    atomicSub(&hist0[b * 256 + (int)(__float_as_uint(nb) >> 24)], 1);
    neg_bce[idx] = 0.0f;
    float bce = -fmaxf(logf(p), -100.0f);
    atomicAdd(&posbce[b], bce);
    atomicAdd(&num_pos[b], 1);
    atomicAdd(&loc_sum[b], loc_term(bbox[idx], gt[b * GG + bix]));
}

// ---------------- radix-select scan of one 8-bit level (256 threads) ----------------
__device__ __forceinline__ void scan_level(const int* __restrict__ histL, int t,
                                           int* ss, int* sres,
                                           unsigned int* prefix, int* k, int shift) {
    int kk = *k;
    ss[t] = histL[t];
    __syncthreads();
#pragma unroll
    for (int off = 1; off < 256; off <<= 1) {
        int v = (t + off < 256) ? ss[t + off] : 0;
        __syncthreads();
        ss[t] += v;
        __syncthreads();
    }
    if (ss[t] >= kk && (t == 255 || ss[t + 1] < kk)) {
        sres[0] = t;
        sres[1] = (t == 255) ? kk : (kk - ss[t + 1]);
    }
    __syncthreads();
    *prefix |= ((unsigned int)sres[0]) << shift;
    *k = sres[1];
    __syncthreads();
}

// ---------------- K3: radix histogram passes 1..3 ----------------
__global__ __launch_bounds__(256) void k_hist(const float* __restrict__ neg_bce,
                                              int* __restrict__ hist,
                                              const int* __restrict__ num_pos,
                                              int pass) {
    const int b = blockIdx.y, t = threadIdx.x;
    __shared__ int ss[256];
    __shared__ int sres[2];
    __shared__ int sh[256];
    int np_ = num_pos[b];
    int k = min(3 * np_, AA - np_);
    if (k <= 0) return;
    unsigned int prefix = 0;
    for (int L = 0; L < pass; ++L)
        scan_level(&hist[(L * BB + b) * 256], t, ss, sres, &prefix, &k, 24 - 8 * L);
    sh[t] = 0;
    __syncthreads();
    const unsigned int pmask = 0xFFFFFFFFu << (32 - 8 * pass);
    const int shift = 24 - 8 * pass;
    for (int a = blockIdx.x * 256 + t; a < AA; a += gridDim.x * 256) {
        unsigned int bits = __float_as_uint(neg_bce[b * AA + a]);
        if ((bits & pmask) == prefix) atomicAdd(&sh[(bits >> shift) & 0xFFu], 1);
    }
    __syncthreads();
    if (sh[t]) atomicAdd(&hist[(pass * BB + b) * 256 + t], sh[t]);
}

// ---------------- K4: sum of values strictly greater than kth value; export vk ----------------
__global__ __launch_bounds__(256) void k_topk(const float* __restrict__ neg_bce,
                                              const int* __restrict__ hist,
                                              const int* __restrict__ num_pos,
                                              float* __restrict__ negsum,
                                              int* __restrict__ ngt,
                                              float* __restrict__ vk_arr) {
    const int b = blockIdx.y, t = threadIdx.x;
    __shared__ int ss[256];
    __shared__ int sres[2];
    __shared__ float sfs[4];
    __shared__ int sfc[4];
    int np_ = num_pos[b];
    int k = min(3 * np_, AA - np_);
    if (k <= 0) return;
    unsigned int prefix = 0;
    for (int L = 0; L < 4; ++L)
        scan_level(&hist[(L * BB + b) * 256], t, ss, sres, &prefix, &k, 24 - 8 * L);
    const float vk = __uint_as_float(prefix);
    if (blockIdx.x == 0 && t == 0) vk_arr[b] = vk;
    float s = 0.0f; int c = 0;
    for (int a = blockIdx.x * 256 + t; a < AA; a += gridDim.x * 256) {
        float v = neg_bce[b * AA + a];
        if (v > vk) { s += v; c++; }
    }
#pragma unroll
    for (int off = 32; off; off >>= 1) { s += __shfl_xor(s, off, 64); c += __shfl_xor(c, off, 64); }
    const int lane = t & 63, wv = t >> 6;
    if (lane == 0) { sfs[wv] = s; sfc[wv] = c; }
    __syncthreads();
    if (t == 0) {
        float S = sfs[0] + sfs[1] + sfs[2] + sfs[3];
        int   C = sfc[0] + sfc[1] + sfc[2] + sfc[3];
        if (S != 0.0f) atomicAdd(&negsum[b], S);
        if (C) atomicAdd(&ngt[b], C);
    }
}

// ---------------- K5: trivial final combine ----------------
__global__ void k_final(const int* __restrict__ num_pos,
                        const float* __restrict__ loc_sum,
                        const float* __restrict__ posbce,
                        const float* __restrict__ negsum,
                        const int* __restrict__ ngt,
                        const float* __restrict__ vk_arr,
                        const int* __restrict__ pred_cnt,
                        const float* __restrict__ miou_s,
                        const int* __restrict__ miou_c,
                        float* __restrict__ out) {
    if (threadIdx.x == 0) {
        int npos_t = 0; float loc_t = 0.0f, conf_t = 0.0f, cnt_t = 0.0f;
        for (int b = 0; b < BB; ++b) {
            int np_ = num_pos[b];
            int k0 = min(3 * np_, AA - np_);
            float add = posbce[b] + negsum[b];
            if (k0 > 0) add += (float)(k0 - ngt[b]) * vk_arr[b];
            conf_t += add;
            npos_t += np_;
            loc_t += loc_sum[b];
            float diff = fabsf((float)(pred_cnt[b] - GG));
            cnt_t += (diff <= 3.0f) ? diff * 0.2f
                                    : 0.6f + 0.2f * logf(fmaxf(diff - 2.0f, 1.0f));
        }
        float total_count = cnt_t / (float)BB;
        float npos = (float)max(1, npos_t);
        float total_loc = loc_t / npos;
        float total_conf = conf_t / npos;
        int C = *miou_c;
        float mean_iou = (C > 0) ? (*miou_s / (float)max(C, 1)) : 0.1f;
        float q = fminf(fmaxf(1.0f - mean_iou, 0.1f), 0.9f);
        float dyn = 1.0f + q;
        out[0] = dyn * total_loc + total_conf + 0.2f * total_count;
        out[1] = total_conf;
        out[2] = total_loc;
        out[3] = total_count;
        out[4] = mean_iou;
    }
}

extern "C" void kernel_launch(void* const* d_in, const int* in_sizes, int n_in,
                              void* d_out, int out_size, void* d_ws, size_t ws_size,
                              hipStream_t stream) {
    (void)in_sizes; (void)n_in; (void)out_size; (void)ws_size;
    const float* bbox    = (const float*)d_in[0];
    const float* conf    = (const float*)d_in[1];
    const float* anchors = (const float*)d_in[2];
    const float* gt      = (const float*)d_in[3];
    char* ws = (char*)d_ws;
    unsigned long long* packed = (unsigned long long*)(ws + OFF_PACKED);
    int*   hist     = (int*)(ws + OFF_HIST);
    int*   num_pos  = (int*)(ws + OFF_NUMPOS);
    float* loc_sum  = (float*)(ws + OFF_LOCSUM);
    float* posbce   = (float*)(ws + OFF_POSBCE);
    int*   pred_cnt = (int*)(ws + OFF_PREDCNT);
    float* negsum   = (float*)(ws + OFF_NEGSUM);
    int*   ngt      = (int*)(ws + OFF_NGT);
    float* miou_s   = (float*)(ws + OFF_MIOU_S);
    int*   miou_c   = (int*)(ws + OFF_MIOU_C);
    float* vk_arr   = (float*)(ws + OFF_VK);
    float* neg_bce  = (float*)(ws + OFF_NEGBCE);

    hipMemsetAsync(d_ws, 0, MEMSET_BYTES, stream);
    k_main<<<dim3(64, BB), 256, 0, stream>>>((const float4*)bbox, conf,
                                             (const float4*)anchors, (const float4*)gt,
                                             packed, neg_bce,
                                             hist, num_pos, loc_sum, posbce, pred_cnt,
                                             miou_s, miou_c);
    k_force<<<1, 512, 0, stream>>>((const float4*)bbox, conf,
                                   (const float4*)anchors, (const float4*)gt,
                                   packed, neg_bce, hist, num_pos, loc_sum, posbce);
    for (int pass = 1; pass <= 3; ++pass)
        k_hist<<<dim3(64, BB), 256, 0, stream>>>(neg_bce, hist, num_pos, pass);
    k_topk<<<dim3(64, BB), 256, 0, stream>>>(neg_bce, hist, num_pos, negsum, ngt, vk_arr);
    k_final<<<1, 64, 0, stream>>>(num_pos, loc_sum, posbce, negsum, ngt, vk_arr,
                                  pred_cnt, miou_s, miou_c, (float*)d_out);
}